// Round 1
// baseline (1293.284 us; speedup 1.0000x reference)
//
#include <hip/hip_runtime.h>
#include <math.h>

// Problem constants (fixed by the reference)
constexpr int Bb = 4;      // batch
constexpr int Cc = 256;    // channels
constexpr int Nn = 4096;   // sequence positions
constexpr int K  = 32;     // qk channels

// ---------------------------------------------------------------------------
// Workspace layout (floats):
//   Ft   : Bb*Nn*K     f transposed  [b][n][k]
//   Gt   : Bb*Nn*K     g transposed  [b][m][k]
//   H    : Bb*Cc*Nn    h             [b][c][n]
//   RMAX : Bb*Nn       row max of S
//   RINV : Bb*Nn       1 / row sum of exp
// total = 2*524288 + 4194304 + 2*16384 = 5,275,648 floats = 20.1 MiB
// ---------------------------------------------------------------------------

// ===== Kernel 1: f,g projections, stored transposed ========================
// grid (Nn/64, Bb), block 256 = 64 n-lanes x 4 k-groups (8 k each)
__global__ __launch_bounds__(256) void proj_fg(
    const float* __restrict__ x, const float* __restrict__ Wf,
    const float* __restrict__ bf, const float* __restrict__ Wg,
    const float* __restrict__ bg, float* __restrict__ Ft, float* __restrict__ Gt)
{
  __shared__ float Ws[64][65];  // [c-in-tile][k: 0..31 = Wf, 32..63 = Wg]
  const int b   = blockIdx.y;
  const int n0  = blockIdx.x * 64;
  const int tid = threadIdx.x;
  const int nl  = tid & 63;
  const int kg  = tid >> 6;     // 0..3
  const int n   = n0 + nl;

  float facc[8], gacc[8];
#pragma unroll
  for (int j = 0; j < 8; ++j) { facc[j] = bf[kg*8+j]; gacc[j] = bg[kg*8+j]; }

  for (int c0 = 0; c0 < Cc; c0 += 64) {
    __syncthreads();
    for (int i = tid; i < 64*64; i += 256) {
      int kk = i >> 6, cc = i & 63;
      float v = (kk < 32) ? Wf[kk*Cc + c0 + cc] : Wg[(kk-32)*Cc + c0 + cc];
      Ws[cc][kk] = v;
    }
    __syncthreads();
    for (int cc = 0; cc < 64; ++cc) {
      float xv = x[(size_t)(b*Cc + c0 + cc)*Nn + n];
      const float* wr  = &Ws[cc][kg*8];
      const float* wr2 = &Ws[cc][32 + kg*8];
#pragma unroll
      for (int j = 0; j < 8; ++j) {
        facc[j] = fmaf(wr[j],  xv, facc[j]);
        gacc[j] = fmaf(wr2[j], xv, gacc[j]);
      }
    }
  }
  float* fo = &Ft[((size_t)b*Nn + n)*K + kg*8];
  float* go = &Gt[((size_t)b*Nn + n)*K + kg*8];
  float4 f0 = {facc[0],facc[1],facc[2],facc[3]}, f1 = {facc[4],facc[5],facc[6],facc[7]};
  float4 g0 = {gacc[0],gacc[1],gacc[2],gacc[3]}, g1 = {gacc[4],gacc[5],gacc[6],gacc[7]};
  *(float4*)&fo[0] = f0; *(float4*)&fo[4] = f1;
  *(float4*)&go[0] = g0; *(float4*)&go[4] = g1;
}

// ===== Kernel 2: h = Wh @ x + bh (tiled fp32 GEMM) =========================
// grid (Nn/64, Cc/64, Bb), block 256; 64x64 tile, 4x4 microtile
__global__ __launch_bounds__(256) void proj_h(
    const float* __restrict__ x, const float* __restrict__ Wh,
    const float* __restrict__ bh, float* __restrict__ H)
{
  __shared__ float Ws[16][68];  // [k][co]  (68: 16B-aligned rows, conflict-safe)
  __shared__ float Xs[16][64];  // [k][n]
  const int b   = blockIdx.z;
  const int n0  = blockIdx.x * 64;
  const int co0 = blockIdx.y * 64;
  const int tid = threadIdx.x;
  const int tx  = tid & 15, ty = tid >> 4;
  float acc[4][4] = {};

  for (int c0 = 0; c0 < Cc; c0 += 16) {
    __syncthreads();
    for (int i = tid; i < 1024; i += 256) {
      int co = i >> 4, kk = i & 15;
      Ws[kk][co] = Wh[(co0+co)*Cc + c0 + kk];
    }
    for (int i = tid; i < 1024; i += 256) {
      int kk = i >> 6, nn = i & 63;
      Xs[kk][nn] = x[(size_t)(b*Cc + c0 + kk)*Nn + n0 + nn];
    }
    __syncthreads();
#pragma unroll
    for (int kk = 0; kk < 16; ++kk) {
      float4 wv = *(const float4*)&Ws[kk][ty*4];
      float4 xv = *(const float4*)&Xs[kk][tx*4];
      float w[4]  = {wv.x,wv.y,wv.z,wv.w};
      float xr[4] = {xv.x,xv.y,xv.z,xv.w};
#pragma unroll
      for (int i2 = 0; i2 < 4; ++i2)
#pragma unroll
        for (int j = 0; j < 4; ++j)
          acc[i2][j] = fmaf(w[i2], xr[j], acc[i2][j]);
    }
  }
#pragma unroll
  for (int i2 = 0; i2 < 4; ++i2) {
    int co = co0 + ty*4 + i2;
    float bb = bh[co];
    float4 o = {acc[i2][0]+bb, acc[i2][1]+bb, acc[i2][2]+bb, acc[i2][3]+bb};
    *(float4*)&H[(size_t)(b*Cc + co)*Nn + n0 + tx*4] = o;
  }
}

// ===== Kernel 3: row softmax stats over S = F^T G ==========================
// grid (Nn/32, Bb), block 256 = 32 rows x 8 m-lanes
__global__ __launch_bounds__(256) void stats_k(
    const float* __restrict__ Ft, const float* __restrict__ Gt,
    float* __restrict__ RMAX, float* __restrict__ RINV)
{
  __shared__ float Gs[128][36];
  const int b   = blockIdx.y;
  const int tid = threadIdx.x;
  const int n   = blockIdx.x * 32 + (tid >> 3);
  const int ml  = tid & 7;

  float4 fv[8];
  const float4* fp = (const float4*)&Ft[((size_t)b*Nn + n)*K];
#pragma unroll
  for (int q = 0; q < 8; ++q) fv[q] = fp[q];

  float mx = -1e30f, l = 0.f;
  for (int m0 = 0; m0 < Nn; m0 += 128) {
    __syncthreads();
    const float4* gp = (const float4*)&Gt[((size_t)b*Nn + m0)*K];
    for (int i = tid; i < 1024; i += 256) {  // 1024 float4 = 128 rows x 32
      float4 v = gp[i];
      int mm = i >> 3, kq = (i & 7) * 4;
      *(float4*)&Gs[mm][kq] = v;
    }
    __syncthreads();
#pragma unroll 2
    for (int it = 0; it < 16; ++it) {
      int mm = ml + it*8;
      const float4* gr = (const float4*)&Gs[mm][0];
      float s0=0.f, s1=0.f, s2=0.f, s3=0.f;
#pragma unroll
      for (int q = 0; q < 8; ++q) {
        float4 a = fv[q], g4 = gr[q];
        s0 = fmaf(a.x, g4.x, s0);
        s1 = fmaf(a.y, g4.y, s1);
        s2 = fmaf(a.z, g4.z, s2);
        s3 = fmaf(a.w, g4.w, s3);
      }
      float s  = (s0+s1)+(s2+s3);
      float nm = fmaxf(mx, s);
      l  = l * __expf(mx - nm) + __expf(s - nm);
      mx = nm;
    }
  }
  // combine the 8 m-lanes of this row (lanes are consecutive, within a wave)
#pragma unroll
  for (int d = 1; d < 8; d <<= 1) {
    float omx = __shfl_xor(mx, d);
    float ol  = __shfl_xor(l,  d);
    float nm  = fmaxf(mx, omx);
    l  = l * __expf(mx - nm) + ol * __expf(omx - nm);
    mx = nm;
  }
  if (ml == 0) {
    RMAX[(size_t)b*Nn + n] = mx;
    RINV[(size_t)b*Nn + n] = 1.0f / l;
  }
}

// ===== Kernel 4: out = gamma * H @ P + x ===================================
// grid (Nn/32, Bb), block 256; tile 256c x 32m; per-thread 8c x 4m
__global__ __launch_bounds__(256) void out_k(
    const float* __restrict__ x, const float* __restrict__ Ft,
    const float* __restrict__ Gt, const float* __restrict__ H,
    const float* __restrict__ RMAX, const float* __restrict__ RINV,
    const float* __restrict__ gamma, float* __restrict__ out)
{
  __shared__ float Gs[32][36];   // block's 32 g columns (resident whole block)
  __shared__ float Hs[16][260];  // h tile transposed [n][c]
  __shared__ float Ps[16][36];   // p tile [n][m]
  __shared__ float Fs[16][36];   // f tile [n][k]
  const int b   = blockIdx.y;
  const int m0  = blockIdx.x * 32;
  const int tid = threadIdx.x;
  const int tx  = tid & 7;        // m-group: m = m0 + tx*4 + mj
  const int ty  = tid >> 3;       // c-group: c = ty*8 + ci
  const int cb  = ty * 8;

  // stage g for this block's m-columns once
  for (int i = tid; i < 32*8; i += 256) {
    int mm = i >> 3, kq = (i & 7) * 4;
    *(float4*)&Gs[mm][kq] = *(const float4*)&Gt[((size_t)b*Nn + m0 + mm)*K + kq];
  }

  float acc[8][4] = {};

  for (int nt0 = 0; nt0 < Nn; nt0 += 16) {
    __syncthreads();  // previous iteration's readers done (also covers Gs stage)
    // stage H tile (transposed) and F tile
    for (int i = tid; i < Cc*16; i += 256) {
      int c = i >> 4, nn = i & 15;
      Hs[nn][c] = H[(size_t)(b*Cc + c)*Nn + nt0 + nn];
    }
    for (int i = tid; i < 16*8; i += 256) {  // 128 float4
      int nn = i >> 3, kq = (i & 7) * 4;
      *(float4*)&Fs[nn][kq] = *(const float4*)&Ft[((size_t)b*Nn + nt0 + nn)*K + kq];
    }
    __syncthreads();
    // compute P subtile: 16n x 32m; thread (pn, pg) does m = pg*2, pg*2+1
    {
      const int pn = tid & 15;
      const int pg = tid >> 4;
      float4 fq[8];
      const float4* fr = (const float4*)&Fs[pn][0];
#pragma unroll
      for (int q = 0; q < 8; ++q) fq[q] = fr[q];
      float mxn = RMAX[(size_t)b*Nn + nt0 + pn];
      float rin = RINV[(size_t)b*Nn + nt0 + pn];
#pragma unroll
      for (int j = 0; j < 2; ++j) {
        int m = pg*2 + j;
        const float4* gr = (const float4*)&Gs[m][0];
        float s0=0.f, s1=0.f, s2=0.f, s3=0.f;
#pragma unroll
        for (int q = 0; q < 8; ++q) {
          float4 a = fq[q], g4 = gr[q];
          s0 = fmaf(a.x, g4.x, s0);
          s1 = fmaf(a.y, g4.y, s1);
          s2 = fmaf(a.z, g4.z, s2);
          s3 = fmaf(a.w, g4.w, s3);
        }
        float s = (s0+s1)+(s2+s3);
        Ps[pn][m] = __expf(s - mxn) * rin;
      }
    }
    __syncthreads();
    // accumulate out tile
#pragma unroll 4
    for (int nn = 0; nn < 16; ++nn) {
      float4 h0 = *(const float4*)&Hs[nn][cb];
      float4 h1 = *(const float4*)&Hs[nn][cb+4];
      float4 pv = *(const float4*)&Ps[nn][tx*4];
      float hh[8] = {h0.x,h0.y,h0.z,h0.w,h1.x,h1.y,h1.z,h1.w};
      float pp[4] = {pv.x,pv.y,pv.z,pv.w};
#pragma unroll
      for (int ci = 0; ci < 8; ++ci)
#pragma unroll
        for (int mj = 0; mj < 4; ++mj)
          acc[ci][mj] = fmaf(hh[ci], pp[mj], acc[ci][mj]);
    }
  }

  const float gm = gamma[0];
#pragma unroll
  for (int ci = 0; ci < 8; ++ci) {
    int c = cb + ci;
    size_t idx = (size_t)(b*Cc + c)*Nn + m0 + tx*4;
    float4 xv = *(const float4*)&x[idx];
    float4 o;
    o.x = fmaf(gm, acc[ci][0], xv.x);
    o.y = fmaf(gm, acc[ci][1], xv.y);
    o.z = fmaf(gm, acc[ci][2], xv.z);
    o.w = fmaf(gm, acc[ci][3], xv.w);
    *(float4*)&out[idx] = o;
  }
}

// ===========================================================================
extern "C" void kernel_launch(void* const* d_in, const int* in_sizes, int n_in,
                              void* d_out, int out_size, void* d_ws, size_t ws_size,
                              hipStream_t stream) {
  (void)in_sizes; (void)n_in; (void)out_size; (void)ws_size;
  const float* x     = (const float*)d_in[0];
  const float* Wf    = (const float*)d_in[1];
  const float* bf    = (const float*)d_in[2];
  const float* Wg    = (const float*)d_in[3];
  const float* bg    = (const float*)d_in[4];
  const float* Wh    = (const float*)d_in[5];
  const float* bh    = (const float*)d_in[6];
  const float* gamma = (const float*)d_in[7];
  float* out = (float*)d_out;

  float* ws   = (float*)d_ws;               // needs 20.2 MiB of d_ws
  float* Ft   = ws;
  float* Gt   = Ft + (size_t)Bb*Nn*K;
  float* H    = Gt + (size_t)Bb*Nn*K;
  float* RMAX = H  + (size_t)Bb*Cc*Nn;
  float* RINV = RMAX + (size_t)Bb*Nn;

  proj_fg<<<dim3(Nn/64, Bb), 256, 0, stream>>>(x, Wf, bf, Wg, bg, Ft, Gt);
  proj_h <<<dim3(Nn/64, Cc/64, Bb), 256, 0, stream>>>(x, Wh, bh, H);
  stats_k<<<dim3(Nn/32, Bb), 256, 0, stream>>>(Ft, Gt, RMAX, RINV);
  out_k  <<<dim3(Nn/32, Bb), 256, 0, stream>>>(x, Ft, Gt, H, RMAX, RINV, gamma, out);
}

// Round 2
// 447.705 us; speedup vs baseline: 2.8887x; 2.8887x over previous
//
#include <hip/hip_runtime.h>
#include <hip/hip_bf16.h>
#include <math.h>

// Problem constants (fixed by the reference)
constexpr int Bb = 4;      // batch
constexpr int Cc = 256;    // channels
constexpr int Nn = 4096;   // sequence positions
constexpr int K  = 32;     // qk channels

typedef __attribute__((ext_vector_type(8))) short short8;   // 8 x bf16 (4 VGPRs)
typedef __attribute__((ext_vector_type(4))) float f32x4;    // MFMA C/D

static __device__ __forceinline__ unsigned short f2bf(float f) {
  union { __hip_bfloat16 h; unsigned short u; } cv;
  cv.h = __float2bfloat16(f);
  return cv.u;
}
static __device__ __forceinline__ unsigned int pack2(float a, float b) {
  return (unsigned int)f2bf(a) | ((unsigned int)f2bf(b) << 16);
}

// ---------------------------------------------------------------------------
// Workspace (bf16 unless noted):
//   Ft : [B][N][32]  f, K-major          1 MB
//   Gt : [B][N][32]  g, K-major          1 MB
//   H  : [B][C][N]   h                   8 MB
//   Z  : [B][N] fp32 softmax log-norm    64 KB   (p[n][m] = exp(S[n][m]-Z[n]))
// ---------------------------------------------------------------------------

// ===== Kernel 1: f,g projections (fp32 math, bf16 store, K-major) ==========
__global__ __launch_bounds__(256) void proj_fg(
    const float* __restrict__ x, const float* __restrict__ Wf,
    const float* __restrict__ bf, const float* __restrict__ Wg,
    const float* __restrict__ bg,
    unsigned short* __restrict__ Ft, unsigned short* __restrict__ Gt)
{
  __shared__ float Ws[64][65];
  const int b   = blockIdx.y;
  const int n0  = blockIdx.x * 64;
  const int tid = threadIdx.x;
  const int nl  = tid & 63;
  const int kg  = tid >> 6;     // 0..3
  const int n   = n0 + nl;

  float facc[8], gacc[8];
#pragma unroll
  for (int j = 0; j < 8; ++j) { facc[j] = bf[kg*8+j]; gacc[j] = bg[kg*8+j]; }

  for (int c0 = 0; c0 < Cc; c0 += 64) {
    __syncthreads();
    for (int i = tid; i < 64*64; i += 256) {
      int kk = i >> 6, cc = i & 63;
      float v = (kk < 32) ? Wf[kk*Cc + c0 + cc] : Wg[(kk-32)*Cc + c0 + cc];
      Ws[cc][kk] = v;
    }
    __syncthreads();
    for (int cc = 0; cc < 64; ++cc) {
      float xv = x[(size_t)(b*Cc + c0 + cc)*Nn + n];
      const float* wr  = &Ws[cc][kg*8];
      const float* wr2 = &Ws[cc][32 + kg*8];
#pragma unroll
      for (int j = 0; j < 8; ++j) {
        facc[j] = fmaf(wr[j],  xv, facc[j]);
        gacc[j] = fmaf(wr2[j], xv, gacc[j]);
      }
    }
  }
  uint4 fv = { pack2(facc[0],facc[1]), pack2(facc[2],facc[3]),
               pack2(facc[4],facc[5]), pack2(facc[6],facc[7]) };
  uint4 gv = { pack2(gacc[0],gacc[1]), pack2(gacc[2],gacc[3]),
               pack2(gacc[4],gacc[5]), pack2(gacc[6],gacc[7]) };
  *(uint4*)(Ft + ((size_t)(b*Nn + n))*K + kg*8) = fv;
  *(uint4*)(Gt + ((size_t)(b*Nn + n))*K + kg*8) = gv;
}

// ===== Kernel 2: h = Wh @ x + bh (fp32 math, bf16 store) ===================
__global__ __launch_bounds__(256) void proj_h(
    const float* __restrict__ x, const float* __restrict__ Wh,
    const float* __restrict__ bh, unsigned short* __restrict__ H)
{
  __shared__ float Ws[16][68];
  __shared__ float Xs[16][64];
  const int b   = blockIdx.z;
  const int n0  = blockIdx.x * 64;
  const int co0 = blockIdx.y * 64;
  const int tid = threadIdx.x;
  const int tx  = tid & 15, ty = tid >> 4;
  float acc[4][4] = {};

  for (int c0 = 0; c0 < Cc; c0 += 16) {
    __syncthreads();
    for (int i = tid; i < 1024; i += 256) {
      int co = i >> 4, kk = i & 15;
      Ws[kk][co] = Wh[(co0+co)*Cc + c0 + kk];
    }
    for (int i = tid; i < 1024; i += 256) {
      int kk = i >> 6, nn = i & 63;
      Xs[kk][nn] = x[(size_t)(b*Cc + c0 + kk)*Nn + n0 + nn];
    }
    __syncthreads();
#pragma unroll
    for (int kk = 0; kk < 16; ++kk) {
      float4 wv = *(const float4*)&Ws[kk][ty*4];
      float4 xv = *(const float4*)&Xs[kk][tx*4];
      float w[4]  = {wv.x,wv.y,wv.z,wv.w};
      float xr[4] = {xv.x,xv.y,xv.z,xv.w};
#pragma unroll
      for (int i2 = 0; i2 < 4; ++i2)
#pragma unroll
        for (int j = 0; j < 4; ++j)
          acc[i2][j] = fmaf(w[i2], xr[j], acc[i2][j]);
    }
  }
#pragma unroll
  for (int i2 = 0; i2 < 4; ++i2) {
    int co = co0 + ty*4 + i2;
    float bb = bh[co];
    uint2 o = { pack2(acc[i2][0]+bb, acc[i2][1]+bb),
                pack2(acc[i2][2]+bb, acc[i2][3]+bb) };
    *(uint2*)(H + (size_t)(b*Cc + co)*Nn + n0 + tx*4) = o;
  }
}

// ===== Kernel 3: Z[n] = 40 + ln( sum_m exp(S[n][m] - 40) ), S via MFMA =====
// grid (Nn/16, Bb), block 256 = 4 waves; wave w sums its m-quarter.
__global__ __launch_bounds__(256) void stats_k(
    const unsigned short* __restrict__ Ft, const unsigned short* __restrict__ Gt,
    float* __restrict__ Z)
{
  __shared__ float red[4][16];
  const int b    = blockIdx.y;
  const int n0   = blockIdx.x * 16;
  const int tid  = threadIdx.x;
  const int wave = tid >> 6, lane = tid & 63;
  const int q    = lane >> 4, col = lane & 15;

  // A-frag: rows n0..n0+15 of F (identical fragments to out_k's S MFMA)
  short8 af = *(const short8*)(Ft + ((size_t)(b*Nn + n0 + col))*K + q*8);
  const unsigned short* gb = Gt + (size_t)b*Nn*K;

  const f32x4 zero = {0.f, 0.f, 0.f, 0.f};
  float l0 = 0.f, l1 = 0.f, l2 = 0.f, l3 = 0.f;
  const int mstart = wave * (Nn/4);
#pragma unroll 4
  for (int ms = 0; ms < Nn/4; ms += 16) {
    const int m = mstart + ms;
    short8 gf = *(const short8*)(gb + (size_t)(m + col)*K + q*8);
    f32x4 s = __builtin_amdgcn_mfma_f32_16x16x32_bf16(af, gf, zero, 0, 0, 0);
    l0 += __expf(s[0] - 40.f);
    l1 += __expf(s[1] - 40.f);
    l2 += __expf(s[2] - 40.f);
    l3 += __expf(s[3] - 40.f);
  }
  // reduce over the 16 col-lanes (xor masks < 16 stay within the quad group)
#pragma unroll
  for (int d = 1; d < 16; d <<= 1) {
    l0 += __shfl_xor(l0, d);
    l1 += __shfl_xor(l1, d);
    l2 += __shfl_xor(l2, d);
    l3 += __shfl_xor(l3, d);
  }
  if (col == 0) {
    float4 v = {l0, l1, l2, l3};
    *(float4*)&red[wave][q*4] = v;   // rows q*4..q*4+3
  }
  __syncthreads();
  if (tid < 16) {
    float t = red[0][tid] + red[1][tid] + red[2][tid] + red[3][tid];
    Z[(size_t)b*Nn + n0 + tid] = 40.f + __logf(t);
  }
}

// ===== Kernel 4: out = gamma * H @ P + x, all-MFMA =========================
// grid (Nn/64 m, Cc/64 c, Bb), block 256 = 4 waves; wave w owns m-sub w*16.
// K-loop over n in steps of 32; barrier-free (Zs read-only, Ps per-wave).
__global__ __launch_bounds__(256) void out_k(
    const float* __restrict__ x, const unsigned short* __restrict__ Ft,
    const unsigned short* __restrict__ Gt, const unsigned short* __restrict__ H,
    const float* __restrict__ Z, const float* __restrict__ gamma,
    float* __restrict__ out)
{
  __shared__ float Zs[Nn];                 // 16 KB
  __shared__ unsigned short Ps[4][16*40];  // per-wave P relayout, 80B row stride
  const int b    = blockIdx.z;
  const int c0   = blockIdx.y * 64;
  const int m0   = blockIdx.x * 64;
  const int tid  = threadIdx.x;
  const int wave = tid >> 6, lane = tid & 63;
  const int q    = lane >> 4, col = lane & 15;

  for (int i = tid; i < Nn/4; i += 256)
    ((float4*)Zs)[i] = ((const float4*)(Z + (size_t)b*Nn))[i];
  __syncthreads();

  const int mw = m0 + wave*16;
  // G fragment for this wave's 16 m-columns: constant over the K-loop
  short8 gf = *(const short8*)(Gt + ((size_t)(b*Nn + mw + col))*K + q*8);

  const unsigned short* Fb = Ft + (size_t)b*Nn*K;
  const unsigned short* Hb = H  + (size_t)b*Cc*Nn;
  unsigned short* Pw = &Ps[wave][0];

  const f32x4 zero = {0.f, 0.f, 0.f, 0.f};
  f32x4 acc0 = zero, acc1 = zero, acc2 = zero, acc3 = zero;

  for (int nt = 0; nt < Nn; nt += 32) {
    // F fragments (rows nt.., nt+16..) — identical across the 4 waves (L1 hits)
    short8 af0 = *(const short8*)(Fb + (size_t)(nt      + col)*K + q*8);
    short8 af1 = *(const short8*)(Fb + (size_t)(nt + 16 + col)*K + q*8);
    // H fragments: A[i=c][k=n], 8 contiguous n per lane
    short8 hf0 = *(const short8*)(Hb + (size_t)(c0      + col)*Nn + nt + q*8);
    short8 hf1 = *(const short8*)(Hb + (size_t)(c0 + 16 + col)*Nn + nt + q*8);
    short8 hf2 = *(const short8*)(Hb + (size_t)(c0 + 32 + col)*Nn + nt + q*8);
    short8 hf3 = *(const short8*)(Hb + (size_t)(c0 + 48 + col)*Nn + nt + q*8);

    // S tiles (bitwise identical to stats_k's)
    f32x4 s0 = __builtin_amdgcn_mfma_f32_16x16x32_bf16(af0, gf, zero, 0, 0, 0);
    f32x4 s1 = __builtin_amdgcn_mfma_f32_16x16x32_bf16(af1, gf, zero, 0, 0, 0);

    float4 z0 = *(const float4*)&Zs[nt + q*4];        // rows q*4..+3
    float4 z1 = *(const float4*)&Zs[nt + 16 + q*4];

    unsigned int u0 = pack2(__expf(s0[0]-z0.x), __expf(s0[1]-z0.y));
    unsigned int u1 = pack2(__expf(s0[2]-z0.z), __expf(s0[3]-z0.w));
    unsigned int u2 = pack2(__expf(s1[0]-z1.x), __expf(s1[1]-z1.y));
    unsigned int u3 = pack2(__expf(s1[2]-z1.z), __expf(s1[3]-z1.w));

    // C-layout -> B-layout relayout via per-wave LDS (stride 40 ushorts = 80B:
    // reads/writes are at worst 2-way bank-aliased, which is free)
    *(unsigned int*)&Pw[col*40 + q*4]          = u0;  // rows 4q, 4q+1
    *(unsigned int*)&Pw[col*40 + q*4 + 2]      = u1;  // rows 4q+2, 4q+3
    *(unsigned int*)&Pw[col*40 + 16 + q*4]     = u2;  // rows 16+4q, 16+4q+1
    *(unsigned int*)&Pw[col*40 + 16 + q*4 + 2] = u3;

    // B-frag: col=m (lane&15), k-rows q*8..q*8+7 (same-wave RAW, no barrier)
    short8 pf = *(const short8*)&Pw[col*40 + q*8];

    acc0 = __builtin_amdgcn_mfma_f32_16x16x32_bf16(hf0, pf, acc0, 0, 0, 0);
    acc1 = __builtin_amdgcn_mfma_f32_16x16x32_bf16(hf1, pf, acc1, 0, 0, 0);
    acc2 = __builtin_amdgcn_mfma_f32_16x16x32_bf16(hf2, pf, acc2, 0, 0, 0);
    acc3 = __builtin_amdgcn_mfma_f32_16x16x32_bf16(hf3, pf, acc3, 0, 0, 0);
  }

  const float gm = gamma[0];
  f32x4 accs[4] = {acc0, acc1, acc2, acc3};
  const int m = mw + col;
#pragma unroll
  for (int ci = 0; ci < 4; ++ci) {
#pragma unroll
    for (int r = 0; r < 4; ++r) {
      int c = c0 + ci*16 + q*4 + r;           // C/D layout: row = q*4+reg
      size_t idx = ((size_t)(b*Cc + c))*Nn + m;
      out[idx] = fmaf(gm, accs[ci][r], x[idx]);
    }
  }
}

// ===========================================================================
extern "C" void kernel_launch(void* const* d_in, const int* in_sizes, int n_in,
                              void* d_out, int out_size, void* d_ws, size_t ws_size,
                              hipStream_t stream) {
  (void)in_sizes; (void)n_in; (void)out_size; (void)ws_size;
  const float* x     = (const float*)d_in[0];
  const float* Wf    = (const float*)d_in[1];
  const float* bf    = (const float*)d_in[2];
  const float* Wg    = (const float*)d_in[3];
  const float* bg    = (const float*)d_in[4];
  const float* Wh    = (const float*)d_in[5];
  const float* bh    = (const float*)d_in[6];
  const float* gamma = (const float*)d_in[7];
  float* out = (float*)d_out;

  unsigned short* Ft = (unsigned short*)d_ws;                  // 1 MB
  unsigned short* Gt = Ft + (size_t)Bb*Nn*K;                   // 1 MB
  unsigned short* H  = Gt + (size_t)Bb*Nn*K;                   // 8 MB
  float*          Z  = (float*)(H + (size_t)Bb*Cc*Nn);         // 64 KB

  proj_fg<<<dim3(Nn/64, Bb), 256, 0, stream>>>(x, Wf, bf, Wg, bg, Ft, Gt);
  proj_h <<<dim3(Nn/64, Cc/64, Bb), 256, 0, stream>>>(x, Wh, bh, H);
  stats_k<<<dim3(Nn/16, Bb), 256, 0, stream>>>(Ft, Gt, Z);
  out_k  <<<dim3(Nn/64, Cc/64, Bb), 256, 0, stream>>>(x, Ft, Gt, H, Z, gamma, out);
}

// Round 3
// 412.018 us; speedup vs baseline: 3.1389x; 1.0866x over previous
//
#include <hip/hip_runtime.h>
#include <hip/hip_bf16.h>
#include <math.h>

// Problem constants (fixed by the reference)
constexpr int Bb = 4;      // batch
constexpr int Cc = 256;    // channels
constexpr int Nn = 4096;   // sequence positions
constexpr int K  = 32;     // qk channels

constexpr float LOG2E = 1.4426950408889634f;
constexpr float C40L  = 40.0f * LOG2E;   // softmax shift in log2 domain

typedef __attribute__((ext_vector_type(8))) short short8;   // 8 x bf16
typedef __attribute__((ext_vector_type(4))) float f32x4;    // MFMA C/D

static __device__ __forceinline__ unsigned short f2bf(float f) {
  union { __hip_bfloat16 h; unsigned short u; } cv;
  cv.h = __float2bfloat16(f);   // RNE
  return cv.u;
}
static __device__ __forceinline__ unsigned int pack2(float a, float b) {
  return (unsigned int)f2bf(a) | ((unsigned int)f2bf(b) << 16);
}
// cheap round-half-up bf16 pack (used only for P, where gamma*softmax damps err)
static __device__ __forceinline__ unsigned int pack2_rb(float a, float b) {
  unsigned int ua = __builtin_bit_cast(unsigned int, a);
  unsigned int ub = __builtin_bit_cast(unsigned int, b);
  return ((ua + 0x8000u) >> 16) | ((ub + 0x8000u) & 0xffff0000u);
}

static __device__ __forceinline__ f32x4 MF(short8 a, short8 b, f32x4 c) {
  return __builtin_amdgcn_mfma_f32_16x16x32_bf16(a, b, c, 0, 0, 0);
}

// ---------------------------------------------------------------------------
// Workspace:
//   Ft  : [B][N][32]  bf16 f, K-major      1 MB
//   Gt  : [B][N][32]  bf16 g, K-major      1 MB
//   H   : [B][C][N]   bf16 h               8 MB
//   xT  : [B][N][C]   bf16 x transposed    8 MB
//   Whb : [C][C]      bf16 Wh              128 KB
//   Z2  : [B][N] fp32: log2-domain softmax norm; p = exp2(s*LOG2E - Z2[n])
// ---------------------------------------------------------------------------

// ===== castW: Wh fp32 -> bf16 ==============================================
__global__ __launch_bounds__(256) void castW(
    const float* __restrict__ Wh, unsigned short* __restrict__ Whb)
{
  int i = (blockIdx.x * 256 + threadIdx.x) * 4;
  float4 v = *(const float4*)&Wh[i];
  uint2 o = { pack2(v.x, v.y), pack2(v.z, v.w) };
  *(uint2*)&Whb[i] = o;
}

// ===== trans_k: xT[b][n][c] = bf16(x[b][c][n]) =============================
// grid (Nn/64, Cc/64, Bb), block 256
__global__ __launch_bounds__(256) void trans_k(
    const float* __restrict__ x, unsigned short* __restrict__ xT)
{
  __shared__ unsigned short Ls[64][65];
  const int b  = blockIdx.z;
  const int n0 = blockIdx.x * 64, c0 = blockIdx.y * 64;
  const int tid = threadIdx.x;
  // read: 4 rounds, each 16 c-rows x 64 n (float4 per thread)
  {
    const int cr = tid >> 4, n4 = (tid & 15) * 4;
#pragma unroll
    for (int rr = 0; rr < 4; ++rr) {
      int c = rr * 16 + cr;
      float4 v = *(const float4*)&x[(size_t)(b*Cc + c0 + c)*Nn + n0 + n4];
      Ls[c][n4+0] = f2bf(v.x); Ls[c][n4+1] = f2bf(v.y);
      Ls[c][n4+2] = f2bf(v.z); Ls[c][n4+3] = f2bf(v.w);
    }
  }
  __syncthreads();
  // write: c-contiguous uint2 per thread
  {
    const int nw = tid >> 4, cw = (tid & 15) * 4;
#pragma unroll
    for (int rr = 0; rr < 4; ++rr) {
      int n = nw + rr * 16;
      unsigned int lo = (unsigned int)Ls[cw+0][n] | ((unsigned int)Ls[cw+1][n] << 16);
      unsigned int hi = (unsigned int)Ls[cw+2][n] | ((unsigned int)Ls[cw+3][n] << 16);
      uint2 o = { lo, hi };
      *(uint2*)&xT[(size_t)(b*Nn + n0 + n)*Cc + c0 + cw] = o;
    }
  }
}

// ===== Kernel 1: f,g projections (fp32 math, bf16 store, K-major) ==========
__global__ __launch_bounds__(256) void proj_fg(
    const float* __restrict__ x, const float* __restrict__ Wf,
    const float* __restrict__ bf, const float* __restrict__ Wg,
    const float* __restrict__ bg,
    unsigned short* __restrict__ Ft, unsigned short* __restrict__ Gt)
{
  __shared__ float Ws[64][65];
  const int b   = blockIdx.y;
  const int n0  = blockIdx.x * 64;
  const int tid = threadIdx.x;
  const int nl  = tid & 63;
  const int kg  = tid >> 6;
  const int n   = n0 + nl;

  float facc[8], gacc[8];
#pragma unroll
  for (int j = 0; j < 8; ++j) { facc[j] = bf[kg*8+j]; gacc[j] = bg[kg*8+j]; }

  for (int c0 = 0; c0 < Cc; c0 += 64) {
    __syncthreads();
    for (int i = tid; i < 64*64; i += 256) {
      int kk = i >> 6, cc = i & 63;
      float v = (kk < 32) ? Wf[kk*Cc + c0 + cc] : Wg[(kk-32)*Cc + c0 + cc];
      Ws[cc][kk] = v;
    }
    __syncthreads();
    for (int cc = 0; cc < 64; ++cc) {
      float xv = x[(size_t)(b*Cc + c0 + cc)*Nn + n];
      const float* wr  = &Ws[cc][kg*8];
      const float* wr2 = &Ws[cc][32 + kg*8];
#pragma unroll
      for (int j = 0; j < 8; ++j) {
        facc[j] = fmaf(wr[j],  xv, facc[j]);
        gacc[j] = fmaf(wr2[j], xv, gacc[j]);
      }
    }
  }
  uint4 fv = { pack2(facc[0],facc[1]), pack2(facc[2],facc[3]),
               pack2(facc[4],facc[5]), pack2(facc[6],facc[7]) };
  uint4 gv = { pack2(gacc[0],gacc[1]), pack2(gacc[2],gacc[3]),
               pack2(gacc[4],gacc[5]), pack2(gacc[6],gacc[7]) };
  *(uint4*)(Ft + ((size_t)(b*Nn + n))*K + kg*8) = fv;
  *(uint4*)(Gt + ((size_t)(b*Nn + n))*K + kg*8) = gv;
}

// ===== Kernel 2: h = Wh @ x + bh via bf16 MFMA, direct-global ==============
// grid (Nn/64, Cc/64, Bb), block 256 = 4 waves; wave = c-16 sub, 4 n-subtiles
__global__ __launch_bounds__(256) void proj_h(
    const unsigned short* __restrict__ xT, const unsigned short* __restrict__ Whb,
    const float* __restrict__ bh, unsigned short* __restrict__ H)
{
  const int b   = blockIdx.z;
  const int n0  = blockIdx.x * 64;
  const int c0  = blockIdx.y * 64;
  const int tid = threadIdx.x;
  const int wave = tid >> 6, lane = tid & 63;
  const int q = lane >> 4, col = lane & 15;
  const int cw = c0 + wave * 16;

  const unsigned short* Arow = Whb + (size_t)(cw + col) * Cc + q*8;
  const unsigned short* Bbase = xT + (size_t)(b*Nn + n0 + col) * Cc + q*8;

  const f32x4 zero = {0.f,0.f,0.f,0.f};
  f32x4 acc[4] = {zero, zero, zero, zero};

  short8 a0 = *(const short8*)(Arow);
  short8 b0[4], b1[4];
#pragma unroll
  for (int j = 0; j < 4; ++j) b0[j] = *(const short8*)(Bbase + (size_t)(j*16)*Cc);

  for (int ks = 0; ks < 256; ks += 64) {
    int k1 = (ks + 32) & 255;
    short8 a1 = *(const short8*)(Arow + k1);
#pragma unroll
    for (int j = 0; j < 4; ++j) b1[j] = *(const short8*)(Bbase + (size_t)(j*16)*Cc + k1);
#pragma unroll
    for (int j = 0; j < 4; ++j) acc[j] = MF(a0, b0[j], acc[j]);
    int k2 = (ks + 64) & 255;
    a0 = *(const short8*)(Arow + k2);
#pragma unroll
    for (int j = 0; j < 4; ++j) b0[j] = *(const short8*)(Bbase + (size_t)(j*16)*Cc + k2);
#pragma unroll
    for (int j = 0; j < 4; ++j) acc[j] = MF(a1, b1[j], acc[j]);
  }

  float4 bb = *(const float4*)&bh[cw + q*4];
  float brs[4] = {bb.x, bb.y, bb.z, bb.w};
#pragma unroll
  for (int j = 0; j < 4; ++j) {
#pragma unroll
    for (int r = 0; r < 4; ++r) {
      int c = cw + q*4 + r;
      int n = n0 + j*16 + col;
      H[(size_t)(b*Cc + c)*Nn + n] = f2bf(acc[j][r] + brs[r]);
    }
  }
}

// ===== Kernel 3: Z2[n] = C40L + log2( sum_m exp2((S-40)*LOG2E) ) ===========
// grid (Nn/32, Bb), block 256 = 4 waves; wave sums its m-quarter; prefetched.
__global__ __launch_bounds__(256) void stats_k(
    const unsigned short* __restrict__ Ft, const unsigned short* __restrict__ Gt,
    float* __restrict__ Z2)
{
  __shared__ float red[4][32];
  const int b = blockIdx.y, n0 = blockIdx.x * 32;
  const int tid = threadIdx.x, wave = tid >> 6, lane = tid & 63;
  const int q = lane >> 4, col = lane & 15;
  const unsigned short* Fb = Ft + (size_t)b*Nn*K;
  const unsigned short* Gb = Gt + (size_t)b*Nn*K;

  short8 af0 = *(const short8*)(Fb + (size_t)(n0 + col)*K + q*8);
  short8 af1 = *(const short8*)(Fb + (size_t)(n0 + 16 + col)*K + q*8);
  const int mq = wave * (Nn/4);
  const f32x4 zero = {0.f,0.f,0.f,0.f};
  float l[8] = {0.f,0.f,0.f,0.f,0.f,0.f,0.f,0.f};

  short8 gfA = *(const short8*)(Gb + (size_t)(mq + col)*K + q*8);
  for (int it = 0; it < 64; it += 2) {
    short8 gfB = *(const short8*)(Gb + (size_t)(mq + (it+1)*16 + col)*K + q*8);
    f32x4 s0 = MF(af0, gfA, zero);
    f32x4 s1 = MF(af1, gfA, zero);
#pragma unroll
    for (int r = 0; r < 4; ++r) {
      l[r]   += __builtin_amdgcn_exp2f(fmaf(s0[r], LOG2E, -C40L));
      l[4+r] += __builtin_amdgcn_exp2f(fmaf(s1[r], LOG2E, -C40L));
    }
    int m2 = mq + (((it + 2) & 63) * 16);
    gfA = *(const short8*)(Gb + (size_t)(m2 + col)*K + q*8);
    s0 = MF(af0, gfB, zero);
    s1 = MF(af1, gfB, zero);
#pragma unroll
    for (int r = 0; r < 4; ++r) {
      l[r]   += __builtin_amdgcn_exp2f(fmaf(s0[r], LOG2E, -C40L));
      l[4+r] += __builtin_amdgcn_exp2f(fmaf(s1[r], LOG2E, -C40L));
    }
  }
#pragma unroll
  for (int d = 1; d < 16; d <<= 1) {
#pragma unroll
    for (int r = 0; r < 8; ++r) l[r] += __shfl_xor(l[r], d);
  }
  if (col == 0) {
    float4 v0 = {l[0], l[1], l[2], l[3]};
    float4 v1 = {l[4], l[5], l[6], l[7]};
    *(float4*)&red[wave][q*4]      = v0;
    *(float4*)&red[wave][16 + q*4] = v1;
  }
  __syncthreads();
  if (tid < 32) {
    float t = red[0][tid] + red[1][tid] + red[2][tid] + red[3][tid];
    Z2[(size_t)b*Nn + n0 + tid] = C40L + __log2f(t);
  }
}

// ===== Kernel 4: out = gamma * H @ P + x — 2-deep pipelined, barrier-free ==
// grid (Nn/64, Bb), block 512 = 8 waves: wave = (mi = w&3 -> 16 m, ch = w>>2
// -> 128 c). Per step (nt += 32): 2 S-MFMA + 8 exp + LDS P relayout + 8 acc.
struct Gen {
  short8 af0, af1;
  float4 z0, z1;
  short8 hf[8];
  short8 pf;
};

__global__ __launch_bounds__(512, 2) void out_k(
    const float* __restrict__ x, const unsigned short* __restrict__ Ft,
    const unsigned short* __restrict__ Gt, const unsigned short* __restrict__ H,
    const float* __restrict__ Z2, const float* __restrict__ gamma,
    float* __restrict__ out)
{
  __shared__ unsigned short Ps[8][2][640];   // per-wave double-buffered P tile
  const int b    = blockIdx.y;
  const int m0   = blockIdx.x * 64;
  const int tid  = threadIdx.x;
  const int wave = tid >> 6, lane = tid & 63;
  const int q    = lane >> 4, col = lane & 15;
  const int mw   = m0 + (wave & 3) * 16;
  const int c0   = (wave >> 2) * 128;

  const unsigned short* Fb = Ft + (size_t)b*Nn*K;
  const unsigned short* Hb = H  + (size_t)b*Cc*Nn;
  const float*          Zb = Z2 + (size_t)b*Nn;

  short8 gf = *(const short8*)(Gt + ((size_t)(b*Nn + mw + col))*K + q*8);

  const f32x4 zero = {0.f,0.f,0.f,0.f};
  f32x4 acc[8] = {zero,zero,zero,zero,zero,zero,zero,zero};

  Gen A, B;

  auto loadAFZ = [&](Gen& G, int nt) {
    G.af0 = *(const short8*)(Fb + (size_t)(nt      + col)*K + q*8);
    G.af1 = *(const short8*)(Fb + (size_t)(nt + 16 + col)*K + q*8);
    G.z0  = *(const float4*)(Zb + nt + q*4);
    G.z1  = *(const float4*)(Zb + nt + 16 + q*4);
  };
  auto loadHF = [&](Gen& G, int nt) {
#pragma unroll
    for (int i = 0; i < 8; ++i)
      G.hf[i] = *(const short8*)(Hb + (size_t)(c0 + i*16 + col)*Nn + nt + q*8);
  };
  auto buildP = [&](Gen& G, int buf) {
    f32x4 s0 = MF(G.af0, gf, zero);
    f32x4 s1 = MF(G.af1, gf, zero);
    unsigned int u0 = pack2_rb(__builtin_amdgcn_exp2f(fmaf(s0[0], LOG2E, -G.z0.x)),
                               __builtin_amdgcn_exp2f(fmaf(s0[1], LOG2E, -G.z0.y)));
    unsigned int u1 = pack2_rb(__builtin_amdgcn_exp2f(fmaf(s0[2], LOG2E, -G.z0.z)),
                               __builtin_amdgcn_exp2f(fmaf(s0[3], LOG2E, -G.z0.w)));
    unsigned int u2 = pack2_rb(__builtin_amdgcn_exp2f(fmaf(s1[0], LOG2E, -G.z1.x)),
                               __builtin_amdgcn_exp2f(fmaf(s1[1], LOG2E, -G.z1.y)));
    unsigned int u3 = pack2_rb(__builtin_amdgcn_exp2f(fmaf(s1[2], LOG2E, -G.z1.z)),
                               __builtin_amdgcn_exp2f(fmaf(s1[3], LOG2E, -G.z1.w)));
    unsigned short* Pb = &Ps[wave][buf][0];
    uint2 w0 = {u0, u1}, w1 = {u2, u3};
    *(uint2*)&Pb[col*40 + q*4]      = w0;   // k rows 4q..4q+3
    *(uint2*)&Pb[col*40 + 16 + q*4] = w1;   // k rows 16+4q..16+4q+3
    G.pf = *(const short8*)&Pb[col*40 + q*8];  // same-wave in-order DS
  };
  auto accum = [&](const Gen& G) {
#pragma unroll
    for (int i = 0; i < 8; ++i) acc[i] = MF(G.hf[i], G.pf, acc[i]);
  };
  // X: gen whose S/P is built at nt (and hf loaded at nt);
  // Y: gen accumulated (from nt-32), then refilled with af/z for nt+32.
  auto pipe_step = [&](int nt, Gen& X, Gen& Y, int buf) {
    accum(Y);
    loadHF(X, nt);
    loadAFZ(Y, (nt + 32) & (Nn - 1));
    buildP(X, buf);
  };

  // prologue: t = 0
  loadAFZ(A, 0);
  loadHF(A, 0);
  buildP(A, 0);
  loadAFZ(B, 32);

  // steady state: t = 1 .. 126 in pairs, then t = 127
  for (int t = 1; t < 127; t += 2) {
    pipe_step(t*32,      B, A, 1);
    pipe_step(t*32 + 32, A, B, 0);
  }
  pipe_step(127*32, B, A, 1);
  accum(B);   // epilogue: step 127

  const float gm = gamma[0];
  const int m = mw + col;
#pragma unroll
  for (int ci = 0; ci < 8; ++ci) {
#pragma unroll
    for (int r = 0; r < 4; ++r) {
      int c = c0 + ci*16 + q*4 + r;
      size_t idx = ((size_t)(b*Cc + c))*Nn + m;
      out[idx] = fmaf(gm, acc[ci][r], x[idx]);
    }
  }
}

// ===========================================================================
extern "C" void kernel_launch(void* const* d_in, const int* in_sizes, int n_in,
                              void* d_out, int out_size, void* d_ws, size_t ws_size,
                              hipStream_t stream) {
  (void)in_sizes; (void)n_in; (void)out_size; (void)ws_size;
  const float* x     = (const float*)d_in[0];
  const float* Wf    = (const float*)d_in[1];
  const float* bf    = (const float*)d_in[2];
  const float* Wg    = (const float*)d_in[3];
  const float* bg    = (const float*)d_in[4];
  const float* Wh    = (const float*)d_in[5];
  const float* bh    = (const float*)d_in[6];
  const float* gamma = (const float*)d_in[7];
  float* out = (float*)d_out;

  unsigned short* Ft  = (unsigned short*)d_ws;                 // 1 MB
  unsigned short* Gt  = Ft  + (size_t)Bb*Nn*K;                 // 1 MB
  unsigned short* H   = Gt  + (size_t)Bb*Nn*K;                 // 8 MB
  unsigned short* xT  = H   + (size_t)Bb*Cc*Nn;                // 8 MB
  unsigned short* Whb = xT  + (size_t)Bb*Nn*Cc;                // 128 KB
  float*          Z2  = (float*)(Whb + (size_t)Cc*Cc);         // 64 KB

  castW  <<<dim3(Cc*Cc/1024), 256, 0, stream>>>(Wh, Whb);
  trans_k<<<dim3(Nn/64, Cc/64, Bb), 256, 0, stream>>>(x, xT);
  proj_fg<<<dim3(Nn/64, Bb), 256, 0, stream>>>(x, Wf, bf, Wg, bg, Ft, Gt);
  proj_h <<<dim3(Nn/64, Cc/64, Bb), 256, 0, stream>>>(xT, Whb, bh, H);
  stats_k<<<dim3(Nn/32, Bb), 256, 0, stream>>>(Ft, Gt, Z2);
  out_k  <<<dim3(Nn/64, Bb), 512, 0, stream>>>(x, Ft, Gt, H, Z2, gamma, out);
}

// Round 4
// 303.756 us; speedup vs baseline: 4.2576x; 1.3564x over previous
//
#include <hip/hip_runtime.h>
#include <hip/hip_bf16.h>
#include <math.h>

// Problem constants (fixed by the reference)
constexpr int Bb = 4;      // batch
constexpr int Cc = 256;    // channels
constexpr int Nn = 4096;   // sequence positions
constexpr int K  = 32;     // qk channels

constexpr float LOG2E = 1.4426950408889634f;
constexpr float C40L  = 40.0f * LOG2E;   // softmax shift, log2 domain

typedef __attribute__((ext_vector_type(8))) short short8;   // 8 x bf16
typedef __attribute__((ext_vector_type(4))) float f32x4;    // MFMA C/D

static __device__ __forceinline__ unsigned int pack2(float a, float b) {
  union { __hip_bfloat162 h2; unsigned int u; } cv;
  cv.h2 = __float22bfloat162_rn(float2{a, b});   // v_cvt_pk_bf16_f32 on gfx950
  return cv.u;
}
static __device__ __forceinline__ unsigned short f2bf(float f) {
  union { __hip_bfloat16 h; unsigned short u; } cv;
  cv.h = __float2bfloat16(f);
  return cv.u;
}
static __device__ __forceinline__ f32x4 MF(short8 a, short8 b, f32x4 c) {
  return __builtin_amdgcn_mfma_f32_16x16x32_bf16(a, b, c, 0, 0, 0);
}
static __device__ __forceinline__ float ex2(float v) {
  return __builtin_amdgcn_exp2f(v);
}

// ---------------------------------------------------------------------------
// Workspace layout:
//   Ft   [B][N][32]  bf16, K-major, PRE-SCALED by LOG2E       1 MB
//   Gt   [B][N][32]  bf16, K-major                            1 MB
//   H    [B][C][N]   bf16                                     8 MB
//   xT   [B][N][C]   bf16 x transposed                        8 MB
//   Whb  [C][C]      bf16 Wh                                  128 KB
//   Wfgb [64][C]     bf16: rows 0..31 Wf, 32..63 Wg           32 KB
//   Z2   [B][N]      fp32 log2-domain norm: p=exp2(S'-Z2)     64 KB
//   Lp   [2][B][N]   fp32 partial softmax sums                128 KB
//   Pout [2][B][C][N] fp32 n-split partial outputs (optional) 32 MB
// ---------------------------------------------------------------------------

// ===== castW: Wh fp32 -> bf16 ==============================================
__global__ __launch_bounds__(256) void castW(
    const float* __restrict__ Wh, unsigned short* __restrict__ Whb)
{
  int i = (blockIdx.x * 256 + threadIdx.x) * 4;
  float4 v = *(const float4*)&Wh[i];
  uint2 o = { pack2(v.x, v.y), pack2(v.z, v.w) };
  *(uint2*)&Whb[i] = o;
}

// ===== castFG: Wf,Wg fp32 -> Wfgb bf16 (64 rows x 256) =====================
__global__ __launch_bounds__(256) void castFG(
    const float* __restrict__ Wf, const float* __restrict__ Wg,
    unsigned short* __restrict__ Wfgb)
{
  int g = (blockIdx.x * 256 + threadIdx.x) * 4;   // 0 .. 16383
  int row = g >> 8, c = g & 255;
  const float* src = (row < 32) ? &Wf[row*Cc + c] : &Wg[(row-32)*Cc + c];
  float4 v = *(const float4*)src;
  uint2 o = { pack2(v.x, v.y), pack2(v.z, v.w) };
  *(uint2*)&Wfgb[g] = o;
}

// ===== trans_k: xT[b][n][c] = bf16(x[b][c][n]) =============================
__global__ __launch_bounds__(256) void trans_k(
    const float* __restrict__ x, unsigned short* __restrict__ xT)
{
  __shared__ unsigned short Ls[64][65];
  const int b  = blockIdx.z;
  const int n0 = blockIdx.x * 64, c0 = blockIdx.y * 64;
  const int tid = threadIdx.x;
  {
    const int cr = tid >> 4, n4 = (tid & 15) * 4;
#pragma unroll
    for (int rr = 0; rr < 4; ++rr) {
      int c = rr * 16 + cr;
      float4 v = *(const float4*)&x[(size_t)(b*Cc + c0 + c)*Nn + n0 + n4];
      Ls[c][n4+0] = f2bf(v.x); Ls[c][n4+1] = f2bf(v.y);
      Ls[c][n4+2] = f2bf(v.z); Ls[c][n4+3] = f2bf(v.w);
    }
  }
  __syncthreads();
  {
    const int nw = tid >> 4, cw = (tid & 15) * 4;
#pragma unroll
    for (int rr = 0; rr < 4; ++rr) {
      int n = nw + rr * 16;
      unsigned int lo = (unsigned int)Ls[cw+0][n] | ((unsigned int)Ls[cw+1][n] << 16);
      unsigned int hi = (unsigned int)Ls[cw+2][n] | ((unsigned int)Ls[cw+3][n] << 16);
      uint2 o = { lo, hi };
      *(uint2*)&xT[(size_t)(b*Nn + n0 + n)*Cc + c0 + cw] = o;
    }
  }
}

// ===== proj_fgM: F' = LOG2E*(Wf x + bf), G = Wg x + bg via MFMA ============
// grid (Nn/64, Bb), block 256 = 4 waves; wave = 16 n-columns.
__global__ __launch_bounds__(256) void proj_fgM(
    const unsigned short* __restrict__ xT, const unsigned short* __restrict__ Wfgb,
    const float* __restrict__ bf, const float* __restrict__ bg,
    unsigned short* __restrict__ Ft, unsigned short* __restrict__ Gt)
{
  const int b = blockIdx.y;
  const int tid = threadIdx.x, wave = tid >> 6, lane = tid & 63;
  const int q = lane >> 4, col = lane & 15;
  const int n = blockIdx.x * 64 + wave * 16 + col;

  const unsigned short* Bp = xT + (size_t)(b*Nn + n)*Cc + q*8;
  const f32x4 zero = {0.f,0.f,0.f,0.f};
  f32x4 af0 = zero, af1 = zero, ag0 = zero, ag1 = zero;
#pragma unroll
  for (int kc = 0; kc < 8; ++kc) {
    short8 bn = *(const short8*)(Bp + kc*32);
    short8 a0 = *(const short8*)(Wfgb + (size_t)( 0 + col)*Cc + kc*32 + q*8);
    short8 a1 = *(const short8*)(Wfgb + (size_t)(16 + col)*Cc + kc*32 + q*8);
    short8 a2 = *(const short8*)(Wfgb + (size_t)(32 + col)*Cc + kc*32 + q*8);
    short8 a3 = *(const short8*)(Wfgb + (size_t)(48 + col)*Cc + kc*32 + q*8);
    af0 = MF(a0, bn, af0); af1 = MF(a1, bn, af1);
    ag0 = MF(a2, bn, ag0); ag1 = MF(a3, bn, ag1);
  }
  float4 bf0 = *(const float4*)&bf[q*4],      bf1 = *(const float4*)&bf[16 + q*4];
  float4 bg0 = *(const float4*)&bg[q*4],      bg1 = *(const float4*)&bg[16 + q*4];
  uint2 F0 = { pack2((af0[0]+bf0.x)*LOG2E, (af0[1]+bf0.y)*LOG2E),
               pack2((af0[2]+bf0.z)*LOG2E, (af0[3]+bf0.w)*LOG2E) };
  uint2 F1 = { pack2((af1[0]+bf1.x)*LOG2E, (af1[1]+bf1.y)*LOG2E),
               pack2((af1[2]+bf1.z)*LOG2E, (af1[3]+bf1.w)*LOG2E) };
  uint2 G0 = { pack2(ag0[0]+bg0.x, ag0[1]+bg0.y), pack2(ag0[2]+bg0.z, ag0[3]+bg0.w) };
  uint2 G1 = { pack2(ag1[0]+bg1.x, ag1[1]+bg1.y), pack2(ag1[2]+bg1.z, ag1[3]+bg1.w) };
  unsigned short* fo = Ft + (size_t)(b*Nn + n)*K;
  unsigned short* go = Gt + (size_t)(b*Nn + n)*K;
  *(uint2*)(fo + q*4) = F0;  *(uint2*)(fo + 16 + q*4) = F1;
  *(uint2*)(go + q*4) = G0;  *(uint2*)(go + 16 + q*4) = G1;
}

// ===== proj_h: h = Wh @ x + bh via bf16 MFMA ===============================
__global__ __launch_bounds__(256) void proj_h(
    const unsigned short* __restrict__ xT, const unsigned short* __restrict__ Whb,
    const float* __restrict__ bh, unsigned short* __restrict__ H)
{
  const int b   = blockIdx.z;
  const int n0  = blockIdx.x * 64;
  const int c0  = blockIdx.y * 64;
  const int tid = threadIdx.x;
  const int wave = tid >> 6, lane = tid & 63;
  const int q = lane >> 4, col = lane & 15;
  const int cw = c0 + wave * 16;

  const unsigned short* Arow = Whb + (size_t)(cw + col) * Cc + q*8;
  const unsigned short* Bbase = xT + (size_t)(b*Nn + n0 + col) * Cc + q*8;

  const f32x4 zero = {0.f,0.f,0.f,0.f};
  f32x4 acc[4] = {zero, zero, zero, zero};

  short8 a0 = *(const short8*)(Arow);
  short8 b0[4], b1[4];
#pragma unroll
  for (int j = 0; j < 4; ++j) b0[j] = *(const short8*)(Bbase + (size_t)(j*16)*Cc);

  for (int ks = 0; ks < 256; ks += 64) {
    int k1 = (ks + 32) & 255;
    short8 a1 = *(const short8*)(Arow + k1);
#pragma unroll
    for (int j = 0; j < 4; ++j) b1[j] = *(const short8*)(Bbase + (size_t)(j*16)*Cc + k1);
#pragma unroll
    for (int j = 0; j < 4; ++j) acc[j] = MF(a0, b0[j], acc[j]);
    int k2 = (ks + 64) & 255;
    a0 = *(const short8*)(Arow + k2);
#pragma unroll
    for (int j = 0; j < 4; ++j) b0[j] = *(const short8*)(Bbase + (size_t)(j*16)*Cc + k2);
#pragma unroll
    for (int j = 0; j < 4; ++j) acc[j] = MF(a1, b1[j], acc[j]);
  }

  float4 bb = *(const float4*)&bh[cw + q*4];
  float brs[4] = {bb.x, bb.y, bb.z, bb.w};
#pragma unroll
  for (int j = 0; j < 4; ++j) {
#pragma unroll
    for (int r = 0; r < 4; ++r) {
      int c = cw + q*4 + r;
      int n = n0 + j*16 + col;
      H[(size_t)(b*Cc + c)*Nn + n] = f2bf(acc[j][r] + brs[r]);
    }
  }
}

// ===== stats_k: partial softmax sums, m-split 2-way ========================
// grid (Nn/32, 2*Bb), block 256 = 4 waves; wave sums 512 m.
__global__ __launch_bounds__(256) void stats_k(
    const unsigned short* __restrict__ Ft, const unsigned short* __restrict__ Gt,
    float* __restrict__ Lp)
{
  __shared__ float red[4][32];
  const int b = blockIdx.y >> 1, ms = blockIdx.y & 1;
  const int n0 = blockIdx.x * 32;
  const int tid = threadIdx.x, wave = tid >> 6, lane = tid & 63;
  const int q = lane >> 4, col = lane & 15;
  const unsigned short* Fb = Ft + (size_t)b*Nn*K;
  const unsigned short* Gb = Gt + (size_t)b*Nn*K;

  short8 af0 = *(const short8*)(Fb + (size_t)(n0      + col)*K + q*8);
  short8 af1 = *(const short8*)(Fb + (size_t)(n0 + 16 + col)*K + q*8);
  const int mq = ms*2048 + wave*512;
  const f32x4 zero = {0.f,0.f,0.f,0.f};
  float l[8] = {0.f,0.f,0.f,0.f,0.f,0.f,0.f,0.f};

  short8 gfA = *(const short8*)(Gb + (size_t)(mq + col)*K + q*8);
  for (int it = 0; it < 32; ++it) {
    short8 gfB = *(const short8*)(Gb + (size_t)(mq + ((it+1)&31)*16 + col)*K + q*8);
    f32x4 s0 = MF(af0, gfA, zero);
    f32x4 s1 = MF(af1, gfA, zero);
#pragma unroll
    for (int r = 0; r < 4; ++r) {
      l[r]   += ex2(s0[r] - C40L);
      l[4+r] += ex2(s1[r] - C40L);
    }
    gfA = gfB;
  }
#pragma unroll
  for (int d = 1; d < 16; d <<= 1) {
#pragma unroll
    for (int r = 0; r < 8; ++r) l[r] += __shfl_xor(l[r], d);
  }
  if (col == 0) {
    float4 v0 = {l[0], l[1], l[2], l[3]};
    float4 v1 = {l[4], l[5], l[6], l[7]};
    *(float4*)&red[wave][q*4]      = v0;
    *(float4*)&red[wave][16 + q*4] = v1;
  }
  __syncthreads();
  if (tid < 32) {
    float t = red[0][tid] + red[1][tid] + red[2][tid] + red[3][tid];
    Lp[((size_t)ms*Bb + b)*Nn + n0 + tid] = t;
  }
}

// ===== zcomb: Z2 = C40L + log2(L0 + L1) ====================================
__global__ __launch_bounds__(256) void zcomb(
    const float* __restrict__ Lp, float* __restrict__ Z2)
{
  int i = blockIdx.x * 256 + threadIdx.x;    // B*N = 16384
  Z2[i] = C40L + __log2f(Lp[i] + Lp[(size_t)Bb*Nn + i]);
}

// ===== out_k: acc = H @ P (n-split partial or final) =======================
// grid (Nn/64, NS*Bb, 2), block 256 = 4 waves; wave = 32m x 64c.
struct Gen { short8 af0, af1; short8 hf[4]; };

__global__ __launch_bounds__(256, 4) void out_k(
    const unsigned short* __restrict__ Ft, const unsigned short* __restrict__ Gt,
    const unsigned short* __restrict__ H, const float* __restrict__ Z2,
    const float* __restrict__ x, const float* __restrict__ gamma,
    float* __restrict__ dst, int nsShift, int spanMask, int nsteps, int finalMode)
{
  __shared__ unsigned short Ps[4][32*40];   // per-wave P tile [m][k], 80B rows
  const int b   = blockIdx.y >> nsShift;
  const int ns  = blockIdx.y & ((1 << nsShift) - 1);
  const int m0  = blockIdx.x * 64;
  const int c0b = blockIdx.z * 128;
  const int tid = threadIdx.x, wave = tid >> 6, lane = tid & 63;
  const int q = lane >> 4, col = lane & 15;
  const int mw  = m0 + (wave & 1) * 32;
  const int c0w = c0b + (wave >> 1) * 64;
  const int nbeg = ns * (spanMask + 1);

  const unsigned short* Fb = Ft + (size_t)b*Nn*K;
  const unsigned short* Hb = H  + (size_t)b*Cc*Nn;
  const float*          Zb = Z2 + (size_t)b*Nn;

  short8 gf0 = *(const short8*)(Gt + (size_t)(b*Nn + mw      + col)*K + q*8);
  short8 gf1 = *(const short8*)(Gt + (size_t)(b*Nn + mw + 16 + col)*K + q*8);

  unsigned short* Pw = &Ps[wave][0];
  const f32x4 zero = {0.f,0.f,0.f,0.f};
  f32x4 acc[2][4];
#pragma unroll
  for (int j = 0; j < 2; ++j)
#pragma unroll
    for (int i = 0; i < 4; ++i) acc[j][i] = zero;

  Gen A, B;
  auto loadGen = [&](Gen& G, int nt) {
    G.af0 = *(const short8*)(Fb + (size_t)(nt      + col)*K + q*8);
    G.af1 = *(const short8*)(Fb + (size_t)(nt + 16 + col)*K + q*8);
#pragma unroll
    for (int i = 0; i < 4; ++i)
      G.hf[i] = *(const short8*)(Hb + (size_t)(c0w + i*16 + col)*Nn + nt + q*8);
  };
  auto step = [&](int nt, Gen& CUR, Gen& NXT) {
    int ntn = nbeg + (((nt - nbeg) + 32) & spanMask);
    loadGen(NXT, ntn);
    float4 z0 = *(const float4*)(Zb + nt + q*4);
    float4 z1 = *(const float4*)(Zb + nt + 16 + q*4);
    f32x4 s00 = MF(CUR.af0, gf0, zero);
    f32x4 s01 = MF(CUR.af0, gf1, zero);
    f32x4 s10 = MF(CUR.af1, gf0, zero);
    f32x4 s11 = MF(CUR.af1, gf1, zero);
    uint2 w00 = { pack2(ex2(s00[0]-z0.x), ex2(s00[1]-z0.y)),
                  pack2(ex2(s00[2]-z0.z), ex2(s00[3]-z0.w)) };
    uint2 w01 = { pack2(ex2(s01[0]-z0.x), ex2(s01[1]-z0.y)),
                  pack2(ex2(s01[2]-z0.z), ex2(s01[3]-z0.w)) };
    uint2 w10 = { pack2(ex2(s10[0]-z1.x), ex2(s10[1]-z1.y)),
                  pack2(ex2(s10[2]-z1.z), ex2(s10[3]-z1.w)) };
    uint2 w11 = { pack2(ex2(s11[0]-z1.x), ex2(s11[1]-z1.y)),
                  pack2(ex2(s11[2]-z1.z), ex2(s11[3]-z1.w)) };
    *(uint2*)&Pw[(     col)*40      + q*4] = w00;   // P[m][k]: k = q*4..+3
    *(uint2*)&Pw[(16 + col)*40      + q*4] = w01;
    *(uint2*)&Pw[(     col)*40 + 16 + q*4] = w10;   // k = 16+q*4..+3
    *(uint2*)&Pw[(16 + col)*40 + 16 + q*4] = w11;
    short8 pf0 = *(const short8*)&Pw[(     col)*40 + q*8];  // same-wave RAW
    short8 pf1 = *(const short8*)&Pw[(16 + col)*40 + q*8];
#pragma unroll
    for (int i = 0; i < 4; ++i) {
      acc[0][i] = MF(CUR.hf[i], pf0, acc[0][i]);
      acc[1][i] = MF(CUR.hf[i], pf1, acc[1][i]);
    }
  };

  loadGen(A, nbeg);
  for (int t = 0; t < nsteps; t += 2) {
    step(nbeg + t*32,      A, B);
    step(nbeg + t*32 + 32, B, A);
  }

  if (finalMode) {
    const float gm = gamma[0];
#pragma unroll
    for (int mj = 0; mj < 2; ++mj) {
      const int m = mw + mj*16 + col;
#pragma unroll
      for (int i = 0; i < 4; ++i) {
#pragma unroll
        for (int r = 0; r < 4; ++r) {
          int c = c0w + i*16 + q*4 + r;
          size_t idx = ((size_t)(b*Cc + c))*Nn + m;
          dst[idx] = fmaf(gm, acc[mj][i][r], x[idx]);
        }
      }
    }
  } else {
    float* Pb = dst + (size_t)ns * Bb * Cc * Nn;
#pragma unroll
    for (int mj = 0; mj < 2; ++mj) {
      const int m = mw + mj*16 + col;
#pragma unroll
      for (int i = 0; i < 4; ++i) {
#pragma unroll
        for (int r = 0; r < 4; ++r) {
          int c = c0w + i*16 + q*4 + r;
          Pb[((size_t)(b*Cc + c))*Nn + m] = acc[mj][i][r];
        }
      }
    }
  }
}

// ===== combine: out = gamma*(P0+P1) + x ====================================
__global__ __launch_bounds__(256) void combine(
    const float* __restrict__ Pout, const float* __restrict__ x,
    const float* __restrict__ gamma, float* __restrict__ out)
{
  size_t i = ((size_t)blockIdx.x * 256 + threadIdx.x) * 4;
  float4 p0 = *(const float4*)&Pout[i];
  float4 p1 = *(const float4*)&Pout[(size_t)Bb*Cc*Nn + i];
  float4 xv = *(const float4*)&x[i];
  const float gm = gamma[0];
  float4 o;
  o.x = fmaf(gm, p0.x + p1.x, xv.x);
  o.y = fmaf(gm, p0.y + p1.y, xv.y);
  o.z = fmaf(gm, p0.z + p1.z, xv.z);
  o.w = fmaf(gm, p0.w + p1.w, xv.w);
  *(float4*)&out[i] = o;
}

// ===========================================================================
extern "C" void kernel_launch(void* const* d_in, const int* in_sizes, int n_in,
                              void* d_out, int out_size, void* d_ws, size_t ws_size,
                              hipStream_t stream) {
  (void)in_sizes; (void)n_in; (void)out_size;
  const float* x     = (const float*)d_in[0];
  const float* Wf    = (const float*)d_in[1];
  const float* bf    = (const float*)d_in[2];
  const float* Wg    = (const float*)d_in[3];
  const float* bg    = (const float*)d_in[4];
  const float* Wh    = (const float*)d_in[5];
  const float* bh    = (const float*)d_in[6];
  const float* gamma = (const float*)d_in[7];
  float* out = (float*)d_out;

  unsigned short* Ft   = (unsigned short*)d_ws;                // 524288 el
  unsigned short* Gt   = Ft   + (size_t)Bb*Nn*K;               // 524288 el
  unsigned short* H    = Gt   + (size_t)Bb*Nn*K;               // 4194304 el
  unsigned short* xT   = H    + (size_t)Bb*Cc*Nn;              // 4194304 el
  unsigned short* Whb  = xT   + (size_t)Bb*Nn*Cc;              // 65536 el
  unsigned short* Wfgb = Whb  + (size_t)Cc*Cc;                 // 16384 el
  float*          Z2   = (float*)(Wfgb + 64*Cc);               // 16384 f
  float*          Lp   = Z2 + (size_t)Bb*Nn;                   // 32768 f
  float*          Pout = Lp + 2*(size_t)Bb*Nn;                 // 8388608 f

  const size_t needNS2 = 19038208ull + (16384ull + 32768 + 8388608) * 4;
  const bool ns2 = ws_size >= needNS2;

  castW   <<<dim3(Cc*Cc/1024), 256, 0, stream>>>(Wh, Whb);
  castFG  <<<dim3(64*Cc/1024), 256, 0, stream>>>(Wf, Wg, Wfgb);
  trans_k <<<dim3(Nn/64, Cc/64, Bb), 256, 0, stream>>>(x, xT);
  proj_fgM<<<dim3(Nn/64, Bb), 256, 0, stream>>>(xT, Wfgb, bf, bg, Ft, Gt);
  proj_h  <<<dim3(Nn/64, Cc/64, Bb), 256, 0, stream>>>(xT, Whb, bh, H);
  stats_k <<<dim3(Nn/32, 2*Bb), 256, 0, stream>>>(Ft, Gt, Lp);
  zcomb   <<<dim3(Bb*Nn/256), 256, 0, stream>>>(Lp, Z2);
  if (ns2) {
    out_k  <<<dim3(Nn/64, 2*Bb, 2), 256, 0, stream>>>(Ft, Gt, H, Z2, x, gamma,
                                                      Pout, 1, 2047, 64, 0);
    combine<<<dim3((size_t)Bb*Cc*Nn/1024), 256, 0, stream>>>(Pout, x, gamma, out);
  } else {
    out_k  <<<dim3(Nn/64, Bb, 2), 256, 0, stream>>>(Ft, Gt, H, Z2, x, gamma,
                                                    out, 0, 4095, 128, 1);
  }
}